// Round 4
// baseline (2446.004 us; speedup 1.0000x reference)
//
#include <hip/hip_runtime.h>
#include <hip/hip_bf16.h>

#define HID 2048
#define NH 32
#define NKV 8
#define HD 64
#define BB 2
#define SS_ 2048

// ---------------------------------------------------------------------------
// K1: fused QKV projection GEMM (fp32).  C = X @ W + b, scattered to
// head-major [B, nh, S, 64] fp32 workspace.
// Tile: BM=64, BN=64, BK=16; 256 threads; 4x4 per thread.
// ---------------------------------------------------------------------------
__global__ __launch_bounds__(256) void proj_kernel(
    const float* __restrict__ X,
    const float* __restrict__ Wq, const float* __restrict__ bq,
    const float* __restrict__ Wk, const float* __restrict__ bk,
    const float* __restrict__ Wv, const float* __restrict__ bv,
    float* __restrict__ qo, float* __restrict__ ko, float* __restrict__ vo)
{
    __shared__ float As[16][64];   // As[k][m]
    __shared__ float Bs[16][64];   // Bs[k][n]
    const int tid = threadIdx.x;
    const int tx = tid & 15, ty = tid >> 4;
    const int m0 = blockIdx.x * 64;
    const int c0 = blockIdx.y * 64;      // global output column tile (0..3071)

    const float* Wsel; const float* bsel; float* dsel; int ldw, col0, nh;
    if (c0 < 2048)      { Wsel = Wq; bsel = bq; dsel = qo; ldw = 2048; col0 = c0;        nh = NH;  }
    else if (c0 < 2560) { Wsel = Wk; bsel = bk; dsel = ko; ldw = 512;  col0 = c0 - 2048; nh = NKV; }
    else                { Wsel = Wv; bsel = bv; dsel = vo; ldw = 512;  col0 = c0 - 2560; nh = NKV; }

    const int a_m  = tid >> 2;          // 0..63
    const int a_k4 = (tid & 3) << 2;    // 0,4,8,12
    const int b_k  = tid >> 4;          // 0..15
    const int b_c  = (tid & 15) << 2;   // 0..60

    float acc[4][4] = {};
    for (int k0 = 0; k0 < HID; k0 += 16) {
        float4 av  = *(const float4*)&X[(size_t)(m0 + a_m) * HID + k0 + a_k4];
        float4 bv4 = *(const float4*)&Wsel[(size_t)(k0 + b_k) * ldw + col0 + b_c];
        __syncthreads();
        As[a_k4 + 0][a_m] = av.x; As[a_k4 + 1][a_m] = av.y;
        As[a_k4 + 2][a_m] = av.z; As[a_k4 + 3][a_m] = av.w;
        *(float4*)&Bs[b_k][b_c] = bv4;
        __syncthreads();
        #pragma unroll
        for (int kk = 0; kk < 16; ++kk) {
            float4 a4 = *(const float4*)&As[kk][ty << 2];
            float4 b4 = *(const float4*)&Bs[kk][tx << 2];
            const float aa[4] = {a4.x, a4.y, a4.z, a4.w};
            const float bb[4] = {b4.x, b4.y, b4.z, b4.w};
            #pragma unroll
            for (int i = 0; i < 4; ++i)
                #pragma unroll
                for (int j = 0; j < 4; ++j)
                    acc[i][j] = fmaf(aa[i], bb[j], acc[i][j]);
        }
    }
    const int h  = col0 >> 6;
    const int cc = tx << 2;
    #pragma unroll
    for (int i = 0; i < 4; ++i) {
        const int m    = m0 + (ty << 2) + i;
        const int bidx = m >> 11;          // / 2048
        const int ss   = m & (SS_ - 1);
        float4 r;
        r.x = acc[i][0] + bsel[col0 + cc + 0];
        r.y = acc[i][1] + bsel[col0 + cc + 1];
        r.z = acc[i][2] + bsel[col0 + cc + 2];
        r.w = acc[i][3] + bsel[col0 + cc + 3];
        *(float4*)&dsel[(((size_t)bidx * nh + h) * SS_ + ss) * HD + cc] = r;
    }
}

// ---------------------------------------------------------------------------
// K2: flash-style attention, fp32.  One block = (b, h, 64 q-rows).
// 256 threads (16x16), each owns a 4x4 patch; online softmax; P via LDS.
// ---------------------------------------------------------------------------
__global__ __launch_bounds__(256) void attn_kernel(
    const float* __restrict__ q, const float* __restrict__ k,
    const float* __restrict__ v, float* __restrict__ o)
{
    __shared__ float Qt[64][64];  // Qt[d][row]
    __shared__ float Kt[64][64];  // Kt[d][col]
    __shared__ float Vs[64][64];  // Vs[row(s)][d]
    __shared__ float Ps[64][64];  // Ps[k][row]
    const int tid = threadIdx.x;
    const int tx = tid & 15, ty = tid >> 4;
    const int qt = blockIdx.x;   // 0..31
    const int h  = blockIdx.y;   // 0..31
    const int b  = blockIdx.z;   // 0..1
    const int hk = h >> 2;

    const float* qb = q + (((size_t)b * NH  + h ) * SS_ + qt * 64) * HD;
    const float* kb = k + (((size_t)b * NKV + hk) * SS_) * HD;
    const float* vb = v + (((size_t)b * NKV + hk) * SS_) * HD;

    const int lr  = tid >> 2;          // 0..63
    const int ld0 = (tid & 3) << 4;    // 0,16,32,48

    #pragma unroll
    for (int u = 0; u < 4; ++u) {
        const int d4 = ld0 + (u << 2);
        float4 t = *(const float4*)&qb[lr * HD + d4];
        Qt[d4 + 0][lr] = t.x; Qt[d4 + 1][lr] = t.y;
        Qt[d4 + 2][lr] = t.z; Qt[d4 + 3][lr] = t.w;
    }

    float m_i[4], l_i[4], acc[4][4] = {};
    #pragma unroll
    for (int i = 0; i < 4; ++i) { m_i[i] = -3.0e38f; l_i[i] = 0.f; }

    for (int t = 0; t < SS_ / 64; ++t) {
        float4 kr[4], vr[4];
        #pragma unroll
        for (int u = 0; u < 4; ++u) {
            const int d4 = ld0 + (u << 2);
            kr[u] = *(const float4*)&kb[(size_t)(t * 64 + lr) * HD + d4];
            vr[u] = *(const float4*)&vb[(size_t)(t * 64 + lr) * HD + d4];
        }
        __syncthreads();
        #pragma unroll
        for (int u = 0; u < 4; ++u) {
            const int d4 = ld0 + (u << 2);
            Kt[d4 + 0][lr] = kr[u].x; Kt[d4 + 1][lr] = kr[u].y;
            Kt[d4 + 2][lr] = kr[u].z; Kt[d4 + 3][lr] = kr[u].w;
            *(float4*)&Vs[lr][d4] = vr[u];
        }
        __syncthreads();

        float sc[4][4] = {};
        #pragma unroll 8
        for (int kk = 0; kk < 64; ++kk) {
            float4 q4 = *(const float4*)&Qt[kk][ty << 2];
            float4 k4 = *(const float4*)&Kt[kk][tx << 2];
            const float qa[4] = {q4.x, q4.y, q4.z, q4.w};
            const float ka[4] = {k4.x, k4.y, k4.z, k4.w};
            #pragma unroll
            for (int i = 0; i < 4; ++i)
                #pragma unroll
                for (int j = 0; j < 4; ++j)
                    sc[i][j] = fmaf(qa[i], ka[j], sc[i][j]);
        }
        #pragma unroll
        for (int i = 0; i < 4; ++i)
            #pragma unroll
            for (int j = 0; j < 4; ++j) sc[i][j] *= 0.125f;

        float pm[4], al[4], rs[4];
        #pragma unroll
        for (int i = 0; i < 4; ++i)
            pm[i] = fmaxf(fmaxf(sc[i][0], sc[i][1]), fmaxf(sc[i][2], sc[i][3]));
        #pragma unroll
        for (int off = 1; off < 16; off <<= 1)
            #pragma unroll
            for (int i = 0; i < 4; ++i)
                pm[i] = fmaxf(pm[i], __shfl_xor(pm[i], off, 16));
        #pragma unroll
        for (int i = 0; i < 4; ++i) {
            const float mn = fmaxf(m_i[i], pm[i]);
            al[i] = expf(m_i[i] - mn);
            rs[i] = 0.f;
            #pragma unroll
            for (int j = 0; j < 4; ++j) {
                const float p = expf(sc[i][j] - mn);
                sc[i][j] = p;
                rs[i] += p;
            }
            m_i[i] = mn;
        }
        #pragma unroll
        for (int off = 1; off < 16; off <<= 1)
            #pragma unroll
            for (int i = 0; i < 4; ++i)
                rs[i] += __shfl_xor(rs[i], off, 16);
        #pragma unroll
        for (int i = 0; i < 4; ++i) l_i[i] = l_i[i] * al[i] + rs[i];

        #pragma unroll
        for (int i = 0; i < 4; ++i)
            #pragma unroll
            for (int j = 0; j < 4; ++j)
                Ps[(tx << 2) + j][(ty << 2) + i] = sc[i][j];
        #pragma unroll
        for (int i = 0; i < 4; ++i)
            #pragma unroll
            for (int j = 0; j < 4; ++j)
                acc[i][j] *= al[i];
        __syncthreads();

        #pragma unroll 8
        for (int kk = 0; kk < 64; ++kk) {
            float4 p4 = *(const float4*)&Ps[kk][ty << 2];
            float4 v4 = *(const float4*)&Vs[kk][tx << 2];
            const float pa[4] = {p4.x, p4.y, p4.z, p4.w};
            const float va[4] = {v4.x, v4.y, v4.z, v4.w};
            #pragma unroll
            for (int i = 0; i < 4; ++i)
                #pragma unroll
                for (int j = 0; j < 4; ++j)
                    acc[i][j] = fmaf(pa[i], va[j], acc[i][j]);
        }
    }

    // epilogue: write [B, S, HID] fp32
    #pragma unroll
    for (int i = 0; i < 4; ++i) {
        const float inv = 1.0f / l_i[i];
        const size_t row = (size_t)b * SS_ + qt * 64 + (ty << 2) + i;
        float4 r;
        r.x = acc[i][0] * inv; r.y = acc[i][1] * inv;
        r.z = acc[i][2] * inv; r.w = acc[i][3] * inv;
        *(float4*)&o[row * HID + h * HD + (tx << 2)] = r;
    }
}

// ---------------------------------------------------------------------------
// K3: output projection GEMM (fp32 accumulate, fp32 store — output is fp32!).
// ---------------------------------------------------------------------------
__global__ __launch_bounds__(256) void oproj_kernel(
    const float* __restrict__ A, const float* __restrict__ Wo,
    const float* __restrict__ bo, float* __restrict__ out)
{
    __shared__ float As[16][64];
    __shared__ float Bs[16][64];
    const int tid = threadIdx.x;
    const int tx = tid & 15, ty = tid >> 4;
    const int m0 = blockIdx.x * 64;
    const int c0 = blockIdx.y * 64;

    const int a_m  = tid >> 2;
    const int a_k4 = (tid & 3) << 2;
    const int b_k  = tid >> 4;
    const int b_c  = (tid & 15) << 2;

    float acc[4][4] = {};
    for (int k0 = 0; k0 < HID; k0 += 16) {
        float4 av  = *(const float4*)&A[(size_t)(m0 + a_m) * HID + k0 + a_k4];
        float4 bv4 = *(const float4*)&Wo[(size_t)(k0 + b_k) * HID + c0 + b_c];
        __syncthreads();
        As[a_k4 + 0][a_m] = av.x; As[a_k4 + 1][a_m] = av.y;
        As[a_k4 + 2][a_m] = av.z; As[a_k4 + 3][a_m] = av.w;
        *(float4*)&Bs[b_k][b_c] = bv4;
        __syncthreads();
        #pragma unroll
        for (int kk = 0; kk < 16; ++kk) {
            float4 a4 = *(const float4*)&As[kk][ty << 2];
            float4 b4 = *(const float4*)&Bs[kk][tx << 2];
            const float aa[4] = {a4.x, a4.y, a4.z, a4.w};
            const float bb[4] = {b4.x, b4.y, b4.z, b4.w};
            #pragma unroll
            for (int i = 0; i < 4; ++i)
                #pragma unroll
                for (int j = 0; j < 4; ++j)
                    acc[i][j] = fmaf(aa[i], bb[j], acc[i][j]);
        }
    }
    const int cc = tx << 2;
    #pragma unroll
    for (int i = 0; i < 4; ++i) {
        const int m = m0 + (ty << 2) + i;
        float4 r;
        r.x = acc[i][0] + bo[c0 + cc + 0];
        r.y = acc[i][1] + bo[c0 + cc + 1];
        r.z = acc[i][2] + bo[c0 + cc + 2];
        r.w = acc[i][3] + bo[c0 + cc + 3];
        *(float4*)&out[(size_t)m * HID + c0 + cc] = r;
    }
}

// ---------------------------------------------------------------------------
extern "C" void kernel_launch(void* const* d_in, const int* in_sizes, int n_in,
                              void* d_out, int out_size, void* d_ws, size_t ws_size,
                              hipStream_t stream) {
    // Input-order hedge (free): dict order has in_sizes[1]==4194304 (Wq);
    // alphabetical order would have in_sizes[1]==1048576 (Wk).
    int iX = 0, iWq = 1, ibq = 2, iWk = 3, ibk = 4, iWv = 5, ibv = 6, iWo = 7, ibo = 8;
    if (n_in == 9 && in_sizes[1] == 1048576) {
        iWk = 1; iWo = 2; iWq = 3; iWv = 4; ibk = 5; ibo = 6; ibq = 7; ibv = 8;
    }
    const float* X  = (const float*)d_in[iX];
    const float* Wq = (const float*)d_in[iWq];
    const float* bq = (const float*)d_in[ibq];
    const float* Wk = (const float*)d_in[iWk];
    const float* bk = (const float*)d_in[ibk];
    const float* Wv = (const float*)d_in[iWv];
    const float* bv = (const float*)d_in[ibv];
    const float* Wo = (const float*)d_in[iWo];
    const float* bo = (const float*)d_in[ibo];
    float* out = (float*)d_out;

    float* qws = (float*)d_ws;                              // [2,32,2048,64] fp32
    float* kws = qws + (size_t)BB * NH  * SS_ * HD;         // [2, 8,2048,64]
    float* vws = kws + (size_t)BB * NKV * SS_ * HD;         // [2, 8,2048,64]
    float* ows = vws + (size_t)BB * NKV * SS_ * HD;         // [2,2048,2048]

    proj_kernel<<<dim3(64, 48), 256, 0, stream>>>(X, Wq, bq, Wk, bk, Wv, bv, qws, kws, vws);
    attn_kernel<<<dim3(32, 32, 2), 256, 0, stream>>>(qws, kws, vws, ows);
    oproj_kernel<<<dim3(64, 32), 256, 0, stream>>>(ows, Wo, bo, out);
}

// Round 5
// 1491.867 us; speedup vs baseline: 1.6396x; 1.6396x over previous
//
#include <hip/hip_runtime.h>
#include <hip/hip_bf16.h>

#define HID 2048
#define NH 32
#define NKV 8
#define HD 64
#define BB 2
#define SS_ 2048

#define QT 128      // q rows per attn block
#define KT 64       // kv rows per tile
#define LDQ 72      // padded inner stride (bf16 elems) for Q/K/Ps
#define LDV 66      // padded inner stride for Vt

typedef unsigned short u16;
typedef __attribute__((ext_vector_type(8))) short bf16x8;
typedef __attribute__((ext_vector_type(4))) float f32x4;

__device__ __forceinline__ u16 f2bf(float f) {
    union { float f; unsigned int i; } v; v.f = f;
    unsigned int lsb = (v.i >> 16) & 1u;
    v.i += 0x7fffu + lsb;               // round-to-nearest-even
    return (u16)(v.i >> 16);
}

// ---------------------------------------------------------------------------
// K1: fused QKV projection GEMM (fp32) — unchanged, verified round 4.
// ---------------------------------------------------------------------------
__global__ __launch_bounds__(256) void proj_kernel(
    const float* __restrict__ X,
    const float* __restrict__ Wq, const float* __restrict__ bq,
    const float* __restrict__ Wk, const float* __restrict__ bk,
    const float* __restrict__ Wv, const float* __restrict__ bv,
    float* __restrict__ qo, float* __restrict__ ko, float* __restrict__ vo)
{
    __shared__ float As[16][64];
    __shared__ float Bs[16][64];
    const int tid = threadIdx.x;
    const int tx = tid & 15, ty = tid >> 4;
    const int m0 = blockIdx.x * 64;
    const int c0 = blockIdx.y * 64;

    const float* Wsel; const float* bsel; float* dsel; int ldw, col0, nh;
    if (c0 < 2048)      { Wsel = Wq; bsel = bq; dsel = qo; ldw = 2048; col0 = c0;        nh = NH;  }
    else if (c0 < 2560) { Wsel = Wk; bsel = bk; dsel = ko; ldw = 512;  col0 = c0 - 2048; nh = NKV; }
    else                { Wsel = Wv; bsel = bv; dsel = vo; ldw = 512;  col0 = c0 - 2560; nh = NKV; }

    const int a_m  = tid >> 2;
    const int a_k4 = (tid & 3) << 2;
    const int b_k  = tid >> 4;
    const int b_c  = (tid & 15) << 2;

    float acc[4][4] = {};
    for (int k0 = 0; k0 < HID; k0 += 16) {
        float4 av  = *(const float4*)&X[(size_t)(m0 + a_m) * HID + k0 + a_k4];
        float4 bv4 = *(const float4*)&Wsel[(size_t)(k0 + b_k) * ldw + col0 + b_c];
        __syncthreads();
        As[a_k4 + 0][a_m] = av.x; As[a_k4 + 1][a_m] = av.y;
        As[a_k4 + 2][a_m] = av.z; As[a_k4 + 3][a_m] = av.w;
        *(float4*)&Bs[b_k][b_c] = bv4;
        __syncthreads();
        #pragma unroll
        for (int kk = 0; kk < 16; ++kk) {
            float4 a4 = *(const float4*)&As[kk][ty << 2];
            float4 b4 = *(const float4*)&Bs[kk][tx << 2];
            const float aa[4] = {a4.x, a4.y, a4.z, a4.w};
            const float bb[4] = {b4.x, b4.y, b4.z, b4.w};
            #pragma unroll
            for (int i = 0; i < 4; ++i)
                #pragma unroll
                for (int j = 0; j < 4; ++j)
                    acc[i][j] = fmaf(aa[i], bb[j], acc[i][j]);
        }
    }
    const int h  = col0 >> 6;
    const int cc = tx << 2;
    #pragma unroll
    for (int i = 0; i < 4; ++i) {
        const int m    = m0 + (ty << 2) + i;
        const int bidx = m >> 11;
        const int ss   = m & (SS_ - 1);
        float4 r;
        r.x = acc[i][0] + bsel[col0 + cc + 0];
        r.y = acc[i][1] + bsel[col0 + cc + 1];
        r.z = acc[i][2] + bsel[col0 + cc + 2];
        r.w = acc[i][3] + bsel[col0 + cc + 3];
        *(float4*)&dsel[(((size_t)bidx * nh + h) * SS_ + ss) * HD + cc] = r;
    }
}

// ---------------------------------------------------------------------------
// K2: flash attention with bf16 MFMA (fp32 softmax/accum).
// Block = (qtile of 128 rows, h, b); 4 waves; wave owns 32 q-rows (2 m-frags).
// A/B frag layout (16x16x32): lane holds outer=lane&15, k=(lane>>4)*8+j
// (8 contiguous bf16 = one ds_read_b128 from row-major [outer][k] LDS).
// C/D: col=lane&15, row=(lane>>4)*4+reg  [verified m89].
// ---------------------------------------------------------------------------
__global__ __launch_bounds__(256) void attn_kernel(
    const float* __restrict__ q, const float* __restrict__ k,
    const float* __restrict__ v, float* __restrict__ o)
{
    __shared__ short Qs[QT][LDQ];   // [qrow][d]
    __shared__ short Ks[KT][LDQ];   // [kvrow][d]
    __shared__ short Vt[HD][LDV];   // [d][kvrow]   (transposed)
    __shared__ short Ps[QT][LDQ];   // [qrow][kvcol] — wave-private row bands

    const int tid = threadIdx.x;
    const int w   = tid >> 6;        // wave 0..3
    const int l   = tid & 63;        // lane
    const int l15 = l & 15;
    const int lg  = l >> 4;          // 0..3
    const int qt  = blockIdx.x;      // 0..15
    const int h   = blockIdx.y;      // 0..31
    const int b   = blockIdx.z;      // 0..1
    const int hk  = h >> 2;

    const float* qb = q + (((size_t)b * NH  + h ) * SS_ + qt * QT) * HD;
    const float* kb = k + (((size_t)b * NKV + hk) * SS_) * HD;
    const float* vb = v + (((size_t)b * NKV + hk) * SS_) * HD;

    // ---- stage Q (128x64 fp32 -> bf16 LDS): thread = (row=tid>>1, d0=(tid&1)*32)
    {
        const int row = tid >> 1, d0 = (tid & 1) * 32;
        #pragma unroll
        for (int u = 0; u < 2; ++u) {           // two 16-element chunks
            float4 f0 = *(const float4*)&qb[(size_t)row * HD + d0 + u * 16 + 0];
            float4 f1 = *(const float4*)&qb[(size_t)row * HD + d0 + u * 16 + 4];
            float4 f2 = *(const float4*)&qb[(size_t)row * HD + d0 + u * 16 + 8];
            float4 f3 = *(const float4*)&qb[(size_t)row * HD + d0 + u * 16 + 12];
            bf16x8 w0, w1;
            w0[0]=(short)f2bf(f0.x); w0[1]=(short)f2bf(f0.y); w0[2]=(short)f2bf(f0.z); w0[3]=(short)f2bf(f0.w);
            w0[4]=(short)f2bf(f1.x); w0[5]=(short)f2bf(f1.y); w0[6]=(short)f2bf(f1.z); w0[7]=(short)f2bf(f1.w);
            w1[0]=(short)f2bf(f2.x); w1[1]=(short)f2bf(f2.y); w1[2]=(short)f2bf(f2.z); w1[3]=(short)f2bf(f2.w);
            w1[4]=(short)f2bf(f3.x); w1[5]=(short)f2bf(f3.y); w1[6]=(short)f2bf(f3.z); w1[7]=(short)f2bf(f3.w);
            *(bf16x8*)&Qs[row][d0 + u * 16]     = w0;
            *(bf16x8*)&Qs[row][d0 + u * 16 + 8] = w1;
        }
    }
    __syncthreads();

    // ---- hoist Q A-frags: qf[mf][kc]
    bf16x8 qf[2][2];
    #pragma unroll
    for (int mf = 0; mf < 2; ++mf)
        #pragma unroll
        for (int kc = 0; kc < 2; ++kc)
            qf[mf][kc] = *(bf16x8*)&Qs[w * 32 + mf * 16 + l15][kc * 32 + lg * 8];

    f32x4 oacc[2][4] = {};
    float m_i[2][4], l_i[2][4];
    #pragma unroll
    for (int mf = 0; mf < 2; ++mf)
        #pragma unroll
        for (int r = 0; r < 4; ++r) { m_i[mf][r] = -3.0e38f; l_i[mf][r] = 0.f; }

    for (int t = 0; t < SS_ / KT; ++t) {
        // ---- stage K row-major
        {
            const int trow = tid >> 2, d0 = (tid & 3) * 16;
            float4 f0 = *(const float4*)&kb[(size_t)(t * KT + trow) * HD + d0 + 0];
            float4 f1 = *(const float4*)&kb[(size_t)(t * KT + trow) * HD + d0 + 4];
            float4 f2 = *(const float4*)&kb[(size_t)(t * KT + trow) * HD + d0 + 8];
            float4 f3 = *(const float4*)&kb[(size_t)(t * KT + trow) * HD + d0 + 12];
            bf16x8 w0, w1;
            w0[0]=(short)f2bf(f0.x); w0[1]=(short)f2bf(f0.y); w0[2]=(short)f2bf(f0.z); w0[3]=(short)f2bf(f0.w);
            w0[4]=(short)f2bf(f1.x); w0[5]=(short)f2bf(f1.y); w0[6]=(short)f2bf(f1.z); w0[7]=(short)f2bf(f1.w);
            w1[0]=(short)f2bf(f2.x); w1[1]=(short)f2bf(f2.y); w1[2]=(short)f2bf(f2.z); w1[3]=(short)f2bf(f2.w);
            w1[4]=(short)f2bf(f3.x); w1[5]=(short)f2bf(f3.y); w1[6]=(short)f2bf(f3.z); w1[7]=(short)f2bf(f3.w);
            *(bf16x8*)&Ks[trow][d0]     = w0;
            *(bf16x8*)&Ks[trow][d0 + 8] = w1;
        }
        // ---- stage V transposed: thread = (vrow=tid&63, vd0=(tid>>6)*16)
        {
            const int vrow = tid & 63, vd0 = (tid >> 6) * 16;
            #pragma unroll
            for (int u = 0; u < 4; ++u) {
                float4 f = *(const float4*)&vb[(size_t)(t * KT + vrow) * HD + vd0 + u * 4];
                Vt[vd0 + u * 4 + 0][vrow] = (short)f2bf(f.x);
                Vt[vd0 + u * 4 + 1][vrow] = (short)f2bf(f.y);
                Vt[vd0 + u * 4 + 2][vrow] = (short)f2bf(f.z);
                Vt[vd0 + u * 4 + 3][vrow] = (short)f2bf(f.w);
            }
        }
        __syncthreads();

        // ---- S = Q K^T  (per wave: 32 rows x 64 kv-cols)
        f32x4 sc[2][4] = {};
        #pragma unroll
        for (int nf = 0; nf < 4; ++nf) {
            #pragma unroll
            for (int kc = 0; kc < 2; ++kc) {
                bf16x8 kf = *(bf16x8*)&Ks[nf * 16 + l15][kc * 32 + lg * 8];
                sc[0][nf] = __builtin_amdgcn_mfma_f32_16x16x32_bf16(qf[0][kc], kf, sc[0][nf], 0, 0, 0);
                sc[1][nf] = __builtin_amdgcn_mfma_f32_16x16x32_bf16(qf[1][kc], kf, sc[1][nf], 0, 0, 0);
            }
        }

        // ---- online softmax (rows = (lg*4+r); cols = nf*16 + l15)
        #pragma unroll
        for (int mf = 0; mf < 2; ++mf) {
            float pm[4], al[4], rs[4];
            #pragma unroll
            for (int r = 0; r < 4; ++r) {
                #pragma unroll
                for (int nf = 0; nf < 4; ++nf) sc[mf][nf][r] *= 0.125f;
                pm[r] = fmaxf(fmaxf(sc[mf][0][r], sc[mf][1][r]),
                              fmaxf(sc[mf][2][r], sc[mf][3][r]));
            }
            #pragma unroll
            for (int off = 1; off < 16; off <<= 1)
                #pragma unroll
                for (int r = 0; r < 4; ++r)
                    pm[r] = fmaxf(pm[r], __shfl_xor(pm[r], off));
            #pragma unroll
            for (int r = 0; r < 4; ++r) {
                const float mn = fmaxf(m_i[mf][r], pm[r]);
                al[r] = __expf(m_i[mf][r] - mn);
                m_i[mf][r] = mn;
                rs[r] = 0.f;
                #pragma unroll
                for (int nf = 0; nf < 4; ++nf) {
                    const float p = __expf(sc[mf][nf][r] - mn);
                    sc[mf][nf][r] = p;
                    rs[r] += p;
                }
            }
            #pragma unroll
            for (int off = 1; off < 16; off <<= 1)
                #pragma unroll
                for (int r = 0; r < 4; ++r)
                    rs[r] += __shfl_xor(rs[r], off);
            #pragma unroll
            for (int r = 0; r < 4; ++r)
                l_i[mf][r] = l_i[mf][r] * al[r] + rs[r];
            #pragma unroll
            for (int nf = 0; nf < 4; ++nf)
                #pragma unroll
                for (int r = 0; r < 4; ++r)
                    oacc[mf][nf][r] *= al[r];
            // write P (wave-private rows -> no barrier needed)
            #pragma unroll
            for (int nf = 0; nf < 4; ++nf)
                #pragma unroll
                for (int r = 0; r < 4; ++r)
                    Ps[w * 32 + mf * 16 + lg * 4 + r][nf * 16 + l15] =
                        (short)f2bf(sc[mf][nf][r]);
        }

        // ---- O += P V   (A = P from Ps, B = V^T from Vt)
        bf16x8 pf[2][2];
        #pragma unroll
        for (int mf = 0; mf < 2; ++mf)
            #pragma unroll
            for (int kc = 0; kc < 2; ++kc)
                pf[mf][kc] = *(bf16x8*)&Ps[w * 32 + mf * 16 + l15][kc * 32 + lg * 8];
        #pragma unroll
        for (int nf = 0; nf < 4; ++nf) {
            #pragma unroll
            for (int kc = 0; kc < 2; ++kc) {
                bf16x8 vf = *(bf16x8*)&Vt[nf * 16 + l15][kc * 32 + lg * 8];
                oacc[0][nf] = __builtin_amdgcn_mfma_f32_16x16x32_bf16(pf[0][kc], vf, oacc[0][nf], 0, 0, 0);
                oacc[1][nf] = __builtin_amdgcn_mfma_f32_16x16x32_bf16(pf[1][kc], vf, oacc[1][nf], 0, 0, 0);
            }
        }
        __syncthreads();   // all waves done reading Ks/Vt before next stage
    }

    // ---- epilogue: write [B*S][HID] fp32
    #pragma unroll
    for (int mf = 0; mf < 2; ++mf)
        #pragma unroll
        for (int r = 0; r < 4; ++r) {
            const float inv = 1.0f / l_i[mf][r];
            const size_t row = (size_t)b * SS_ + qt * QT + w * 32 + mf * 16 + lg * 4 + r;
            #pragma unroll
            for (int nf = 0; nf < 4; ++nf)
                o[row * HID + h * HD + nf * 16 + l15] = oacc[mf][nf][r] * inv;
        }
}

// ---------------------------------------------------------------------------
// K3: output projection GEMM (fp32) — unchanged, verified round 4.
// ---------------------------------------------------------------------------
__global__ __launch_bounds__(256) void oproj_kernel(
    const float* __restrict__ A, const float* __restrict__ Wo,
    const float* __restrict__ bo, float* __restrict__ out)
{
    __shared__ float As[16][64];
    __shared__ float Bs[16][64];
    const int tid = threadIdx.x;
    const int tx = tid & 15, ty = tid >> 4;
    const int m0 = blockIdx.x * 64;
    const int c0 = blockIdx.y * 64;

    const int a_m  = tid >> 2;
    const int a_k4 = (tid & 3) << 2;
    const int b_k  = tid >> 4;
    const int b_c  = (tid & 15) << 2;

    float acc[4][4] = {};
    for (int k0 = 0; k0 < HID; k0 += 16) {
        float4 av  = *(const float4*)&A[(size_t)(m0 + a_m) * HID + k0 + a_k4];
        float4 bv4 = *(const float4*)&Wo[(size_t)(k0 + b_k) * HID + c0 + b_c];
        __syncthreads();
        As[a_k4 + 0][a_m] = av.x; As[a_k4 + 1][a_m] = av.y;
        As[a_k4 + 2][a_m] = av.z; As[a_k4 + 3][a_m] = av.w;
        *(float4*)&Bs[b_k][b_c] = bv4;
        __syncthreads();
        #pragma unroll
        for (int kk = 0; kk < 16; ++kk) {
            float4 a4 = *(const float4*)&As[kk][ty << 2];
            float4 b4 = *(const float4*)&Bs[kk][tx << 2];
            const float aa[4] = {a4.x, a4.y, a4.z, a4.w};
            const float bb[4] = {b4.x, b4.y, b4.z, b4.w};
            #pragma unroll
            for (int i = 0; i < 4; ++i)
                #pragma unroll
                for (int j = 0; j < 4; ++j)
                    acc[i][j] = fmaf(aa[i], bb[j], acc[i][j]);
        }
    }
    const int cc = tx << 2;
    #pragma unroll
    for (int i = 0; i < 4; ++i) {
        const int m = m0 + (ty << 2) + i;
        float4 r;
        r.x = acc[i][0] + bo[c0 + cc + 0];
        r.y = acc[i][1] + bo[c0 + cc + 1];
        r.z = acc[i][2] + bo[c0 + cc + 2];
        r.w = acc[i][3] + bo[c0 + cc + 3];
        *(float4*)&out[(size_t)m * HID + c0 + cc] = r;
    }
}

// ---------------------------------------------------------------------------
extern "C" void kernel_launch(void* const* d_in, const int* in_sizes, int n_in,
                              void* d_out, int out_size, void* d_ws, size_t ws_size,
                              hipStream_t stream) {
    int iX = 0, iWq = 1, ibq = 2, iWk = 3, ibk = 4, iWv = 5, ibv = 6, iWo = 7, ibo = 8;
    if (n_in == 9 && in_sizes[1] == 1048576) {   // alphabetical-order hedge
        iWk = 1; iWo = 2; iWq = 3; iWv = 4; ibk = 5; ibo = 6; ibq = 7; ibv = 8;
    }
    const float* X  = (const float*)d_in[iX];
    const float* Wq = (const float*)d_in[iWq];
    const float* bq = (const float*)d_in[ibq];
    const float* Wk = (const float*)d_in[iWk];
    const float* bk = (const float*)d_in[ibk];
    const float* Wv = (const float*)d_in[iWv];
    const float* bv = (const float*)d_in[ibv];
    const float* Wo = (const float*)d_in[iWo];
    const float* bo = (const float*)d_in[ibo];
    float* out = (float*)d_out;

    float* qws = (float*)d_ws;                              // [2,32,2048,64] fp32
    float* kws = qws + (size_t)BB * NH  * SS_ * HD;         // [2, 8,2048,64]
    float* vws = kws + (size_t)BB * NKV * SS_ * HD;         // [2, 8,2048,64]
    float* ows = vws + (size_t)BB * NKV * SS_ * HD;         // [2,2048,2048]

    proj_kernel<<<dim3(64, 48), 256, 0, stream>>>(X, Wq, bq, Wk, bk, Wv, bv, qws, kws, vws);
    attn_kernel<<<dim3(16, 32, 2), 256, 0, stream>>>(qws, kws, vws, ows);
    oproj_kernel<<<dim3(64, 32), 256, 0, stream>>>(ows, Wo, bo, out);
}

// Round 6
// 421.755 us; speedup vs baseline: 5.7996x; 3.5373x over previous
//
#include <hip/hip_runtime.h>
#include <hip/hip_bf16.h>

#define HID 2048
#define NH 32
#define NKV 8
#define HD 64
#define BB 2
#define SS_ 2048
#define MM (BB * SS_)     // 4096 rows

#define QT 128            // q rows per attn block
#define KT 64             // kv rows per tile
#define LDK 72            // padded stride (bf16) for Ks/Ps
#define LDV 66            // padded stride for Vt

typedef unsigned short u16;
typedef __attribute__((ext_vector_type(8))) short bf16x8;
typedef __attribute__((ext_vector_type(4))) float f32x4;

__device__ __forceinline__ u16 f2bf(float f) {
    union { float f; unsigned int i; } v; v.f = f;
    unsigned int lsb = (v.i >> 16) & 1u;
    v.i += 0x7fffu + lsb;               // round-to-nearest-even
    return (u16)(v.i >> 16);
}

// ---------------------------------------------------------------------------
// K0a: straight fp32 -> bf16 convert (X)
// ---------------------------------------------------------------------------
__global__ __launch_bounds__(256) void cvt_kernel(
    const float* __restrict__ in, u16* __restrict__ out, int n4)
{
    const int i = blockIdx.x * 256 + threadIdx.x;
    if (i < n4) {
        float4 f = ((const float4*)in)[i];
        ushort4 r;
        r.x = f2bf(f.x); r.y = f2bf(f.y); r.z = f2bf(f.z); r.w = f2bf(f.w);
        ((ushort4*)out)[i] = r;
    }
}

// ---------------------------------------------------------------------------
// K0b: transpose-convert weights: fp32 [K][N] -> bf16 [N][K].
// 64x64 tiles via LDS [64][65] fp32 (2-way max on both phases = free).
// blockIdx.y selects tensor: [Wq 32 | Wk 8 | Wv 8 | Wo 32] tiles.
// ---------------------------------------------------------------------------
__global__ __launch_bounds__(256) void tw_kernel(
    const float* __restrict__ Wq, const float* __restrict__ Wk,
    const float* __restrict__ Wv, const float* __restrict__ Wo,
    u16* __restrict__ Tq, u16* __restrict__ Tk,
    u16* __restrict__ Tv, u16* __restrict__ To)
{
    __shared__ float tile[64][65];
    const int by = blockIdx.y;
    const float* W; u16* T; int N, n0;
    if (by < 32)      { W = Wq; T = Tq; N = 2048; n0 = by * 64; }
    else if (by < 40) { W = Wk; T = Tk; N = 512;  n0 = (by - 32) * 64; }
    else if (by < 48) { W = Wv; T = Tv; N = 512;  n0 = (by - 40) * 64; }
    else              { W = Wo; T = To; N = 2048; n0 = (by - 48) * 64; }
    const int k0 = blockIdx.x * 64;
    const int r  = threadIdx.x >> 2;          // 0..63
    const int c0 = (threadIdx.x & 3) << 4;    // 0,16,32,48
    #pragma unroll
    for (int u = 0; u < 4; ++u) {
        float4 f = *(const float4*)&W[(size_t)(k0 + r) * N + n0 + c0 + u * 4];
        tile[r][c0 + u * 4 + 0] = f.x; tile[r][c0 + u * 4 + 1] = f.y;
        tile[r][c0 + u * 4 + 2] = f.z; tile[r][c0 + u * 4 + 3] = f.w;
    }
    __syncthreads();
    #pragma unroll
    for (int u = 0; u < 4; ++u) {
        ushort4 o;
        o.x = f2bf(tile[c0 + u * 4 + 0][r]);
        o.y = f2bf(tile[c0 + u * 4 + 1][r]);
        o.z = f2bf(tile[c0 + u * 4 + 2][r]);
        o.w = f2bf(tile[c0 + u * 4 + 3][r]);
        *(ushort4*)&T[(size_t)(n0 + r) * HID + k0 + c0 + u * 4] = o;
    }
}

// ---------------------------------------------------------------------------
// K1: QKV projection, bf16 MFMA.  C = Xb @ W^T-layout + b.
// 128x128 tile, BK=32, 4 waves (2x2), wave = 64x64 = 4x4 16x16 frags.
// A,B LDS layout [outer][k] pad 36 (18-bank stride -> conflict-free b128).
// Epilogue scatters bf16 to head-major q/k/v workspace.
// ---------------------------------------------------------------------------
__global__ __launch_bounds__(256) void proj_kernel(
    const u16* __restrict__ Xb,
    const u16* __restrict__ Tq, const u16* __restrict__ Tk, const u16* __restrict__ Tv,
    const float* __restrict__ bq, const float* __restrict__ bk, const float* __restrict__ bv,
    u16* __restrict__ qo, u16* __restrict__ ko, u16* __restrict__ vo)
{
    __shared__ u16 Al[128][36];
    __shared__ u16 Bl[128][36];
    const int tid = threadIdx.x;
    const int w = tid >> 6, l15 = tid & 15, lg = (tid & 63) >> 4;
    const int wr = w >> 1, wc = w & 1;
    const int m0 = blockIdx.x * 128;
    const int n0 = blockIdx.y * 128;

    const u16* Bt; const float* bias; u16* dst; int nh, nb;
    if (n0 < 2048)      { Bt = Tq + (size_t)n0 * HID;          bias = bq + n0;          dst = qo; nh = NH;  nb = n0; }
    else if (n0 < 2560) { Bt = Tk + (size_t)(n0 - 2048) * HID; bias = bk + (n0 - 2048); dst = ko; nh = NKV; nb = n0 - 2048; }
    else                { Bt = Tv + (size_t)(n0 - 2560) * HID; bias = bv + (n0 - 2560); dst = vo; nh = NKV; nb = n0 - 2560; }

    const int sm = tid >> 2;            // 0..63
    const int sk = (tid & 3) << 3;      // 0,8,16,24

    f32x4 acc[4][4] = {};
    for (int k0 = 0; k0 < HID; k0 += 32) {
        bf16x8 a0 = *(const bf16x8*)&Xb[(size_t)(m0 + sm) * HID + k0 + sk];
        bf16x8 a1 = *(const bf16x8*)&Xb[(size_t)(m0 + 64 + sm) * HID + k0 + sk];
        bf16x8 b0 = *(const bf16x8*)&Bt[(size_t)sm * HID + k0 + sk];
        bf16x8 b1 = *(const bf16x8*)&Bt[(size_t)(64 + sm) * HID + k0 + sk];
        __syncthreads();
        *(bf16x8*)&Al[sm][sk]      = a0;
        *(bf16x8*)&Al[64 + sm][sk] = a1;
        *(bf16x8*)&Bl[sm][sk]      = b0;
        *(bf16x8*)&Bl[64 + sm][sk] = b1;
        __syncthreads();
        bf16x8 af[4], bfr[4];
        #pragma unroll
        for (int i = 0; i < 4; ++i) {
            af[i]  = *(const bf16x8*)&Al[wr * 64 + i * 16 + l15][lg * 8];
            bfr[i] = *(const bf16x8*)&Bl[wc * 64 + i * 16 + l15][lg * 8];
        }
        #pragma unroll
        for (int mf = 0; mf < 4; ++mf)
            #pragma unroll
            for (int nf = 0; nf < 4; ++nf)
                acc[mf][nf] = __builtin_amdgcn_mfma_f32_16x16x32_bf16(af[mf], bfr[nf], acc[mf][nf], 0, 0, 0);
    }

    // epilogue: scatter to head-major [B, nh, S, 64] bf16
    #pragma unroll
    for (int nf = 0; nf < 4; ++nf) {
        const int cl = nb + wc * 64 + nf * 16 + l15;   // col within tensor
        const int hh = cl >> 6, dd = cl & 63;
        const float bv_ = bias[wc * 64 + nf * 16 + l15];
        #pragma unroll
        for (int mf = 0; mf < 4; ++mf)
            #pragma unroll
            for (int r = 0; r < 4; ++r) {
                const int m = m0 + wr * 64 + mf * 16 + lg * 4 + r;
                const int bb_ = m >> 11, ss = m & (SS_ - 1);
                dst[(((size_t)bb_ * nh + hh) * SS_ + ss) * HD + dd] = f2bf(acc[mf][nf][r] + bv_);
            }
    }
}

// ---------------------------------------------------------------------------
// K2: flash attention, bf16 MFMA, bf16 I/O (fp32 softmax/accum).
// Block = (128 q-rows, h, b); 4 waves; wave owns 32 q-rows.
// ---------------------------------------------------------------------------
__global__ __launch_bounds__(256) void attn_kernel(
    const u16* __restrict__ q, const u16* __restrict__ k,
    const u16* __restrict__ v, u16* __restrict__ o)
{
    __shared__ u16 Ks[KT][LDK];     // [kvrow][d]
    __shared__ u16 Vt[HD][LDV];     // [d][kvrow]
    __shared__ u16 Ps[QT][LDK];     // [qrow][kvcol] — wave-private bands

    const int tid = threadIdx.x;
    const int w   = tid >> 6;
    const int l   = tid & 63;
    const int l15 = l & 15;
    const int lg  = l >> 4;
    const int qt  = blockIdx.x;
    const int h   = blockIdx.y;
    const int b   = blockIdx.z;
    const int hk  = h >> 2;

    const u16* qb = q + (((size_t)b * NH  + h ) * SS_ + qt * QT) * HD;
    const u16* kb = k + (((size_t)b * NKV + hk) * SS_) * HD;
    const u16* vb = v + (((size_t)b * NKV + hk) * SS_) * HD;

    // Q A-frags straight from global (bf16, row-major [row][64])
    bf16x8 qf[2][2];
    #pragma unroll
    for (int mf = 0; mf < 2; ++mf)
        #pragma unroll
        for (int kc = 0; kc < 2; ++kc)
            qf[mf][kc] = *(const bf16x8*)&qb[(size_t)(w * 32 + mf * 16 + l15) * HD + kc * 32 + lg * 8];

    f32x4 oacc[2][4] = {};
    float m_i[2][4], l_i[2][4];
    #pragma unroll
    for (int mf = 0; mf < 2; ++mf)
        #pragma unroll
        for (int r = 0; r < 4; ++r) { m_i[mf][r] = -3.0e38f; l_i[mf][r] = 0.f; }

    const int trow = tid >> 2, c16 = (tid & 3) << 4;      // K staging
    const int vrow = tid & 63, vd0 = (tid >> 6) << 4;     // V staging

    for (int t = 0; t < SS_ / KT; ++t) {
        bf16x8 kv0 = *(const bf16x8*)&kb[(size_t)(t * KT + trow) * HD + c16];
        bf16x8 kv1 = *(const bf16x8*)&kb[(size_t)(t * KT + trow) * HD + c16 + 8];
        ushort4 vv[4];
        #pragma unroll
        for (int u = 0; u < 4; ++u)
            vv[u] = *(const ushort4*)&vb[(size_t)(t * KT + vrow) * HD + vd0 + u * 4];
        __syncthreads();
        *(bf16x8*)&Ks[trow][c16]     = kv0;
        *(bf16x8*)&Ks[trow][c16 + 8] = kv1;
        #pragma unroll
        for (int u = 0; u < 4; ++u) {
            Vt[vd0 + u * 4 + 0][vrow] = vv[u].x;
            Vt[vd0 + u * 4 + 1][vrow] = vv[u].y;
            Vt[vd0 + u * 4 + 2][vrow] = vv[u].z;
            Vt[vd0 + u * 4 + 3][vrow] = vv[u].w;
        }
        __syncthreads();

        // S = Q K^T
        f32x4 sc[2][4] = {};
        #pragma unroll
        for (int nf = 0; nf < 4; ++nf)
            #pragma unroll
            for (int kc = 0; kc < 2; ++kc) {
                bf16x8 kf = *(bf16x8*)&Ks[nf * 16 + l15][kc * 32 + lg * 8];
                sc[0][nf] = __builtin_amdgcn_mfma_f32_16x16x32_bf16(qf[0][kc], kf, sc[0][nf], 0, 0, 0);
                sc[1][nf] = __builtin_amdgcn_mfma_f32_16x16x32_bf16(qf[1][kc], kf, sc[1][nf], 0, 0, 0);
            }

        // online softmax
        #pragma unroll
        for (int mf = 0; mf < 2; ++mf) {
            float pm[4], al[4], rs[4];
            #pragma unroll
            for (int r = 0; r < 4; ++r) {
                #pragma unroll
                for (int nf = 0; nf < 4; ++nf) sc[mf][nf][r] *= 0.125f;
                pm[r] = fmaxf(fmaxf(sc[mf][0][r], sc[mf][1][r]),
                              fmaxf(sc[mf][2][r], sc[mf][3][r]));
            }
            #pragma unroll
            for (int off = 1; off < 16; off <<= 1)
                #pragma unroll
                for (int r = 0; r < 4; ++r)
                    pm[r] = fmaxf(pm[r], __shfl_xor(pm[r], off));
            #pragma unroll
            for (int r = 0; r < 4; ++r) {
                const float mn = fmaxf(m_i[mf][r], pm[r]);
                al[r] = __expf(m_i[mf][r] - mn);
                m_i[mf][r] = mn;
                rs[r] = 0.f;
                #pragma unroll
                for (int nf = 0; nf < 4; ++nf) {
                    const float p = __expf(sc[mf][nf][r] - mn);
                    sc[mf][nf][r] = p;
                    rs[r] += p;
                }
            }
            #pragma unroll
            for (int off = 1; off < 16; off <<= 1)
                #pragma unroll
                for (int r = 0; r < 4; ++r)
                    rs[r] += __shfl_xor(rs[r], off);
            #pragma unroll
            for (int r = 0; r < 4; ++r)
                l_i[mf][r] = l_i[mf][r] * al[r] + rs[r];
            #pragma unroll
            for (int nf = 0; nf < 4; ++nf)
                #pragma unroll
                for (int r = 0; r < 4; ++r)
                    oacc[mf][nf][r] *= al[r];
            #pragma unroll
            for (int nf = 0; nf < 4; ++nf)
                #pragma unroll
                for (int r = 0; r < 4; ++r)
                    Ps[w * 32 + mf * 16 + lg * 4 + r][nf * 16 + l15] =
                        f2bf(sc[mf][nf][r]);
        }

        // O += P V
        bf16x8 pf[2][2];
        #pragma unroll
        for (int mf = 0; mf < 2; ++mf)
            #pragma unroll
            for (int kc = 0; kc < 2; ++kc)
                pf[mf][kc] = *(bf16x8*)&Ps[w * 32 + mf * 16 + l15][kc * 32 + lg * 8];
        #pragma unroll
        for (int nf = 0; nf < 4; ++nf)
            #pragma unroll
            for (int kc = 0; kc < 2; ++kc) {
                bf16x8 vf = *(bf16x8*)&Vt[nf * 16 + l15][kc * 32 + lg * 8];
                oacc[0][nf] = __builtin_amdgcn_mfma_f32_16x16x32_bf16(pf[0][kc], vf, oacc[0][nf], 0, 0, 0);
                oacc[1][nf] = __builtin_amdgcn_mfma_f32_16x16x32_bf16(pf[1][kc], vf, oacc[1][nf], 0, 0, 0);
            }
        __syncthreads();
    }

    // epilogue: bf16 [B*S][HID]
    #pragma unroll
    for (int mf = 0; mf < 2; ++mf)
        #pragma unroll
        for (int r = 0; r < 4; ++r) {
            const float inv = 1.0f / l_i[mf][r];
            const size_t row = (size_t)b * SS_ + qt * QT + w * 32 + mf * 16 + lg * 4 + r;
            #pragma unroll
            for (int nf = 0; nf < 4; ++nf)
                o[row * HID + h * HD + nf * 16 + l15] = f2bf(oacc[mf][nf][r] * inv);
        }
}

// ---------------------------------------------------------------------------
// K3: output projection, bf16 MFMA: out = Ob @ Wo (+bo), fp32 store.
// Same 128x128x32 structure as proj.
// ---------------------------------------------------------------------------
__global__ __launch_bounds__(256) void oproj_kernel(
    const u16* __restrict__ Ab, const u16* __restrict__ To,
    const float* __restrict__ bo, float* __restrict__ out)
{
    __shared__ u16 Al[128][36];
    __shared__ u16 Bl[128][36];
    const int tid = threadIdx.x;
    const int w = tid >> 6, l15 = tid & 15, lg = (tid & 63) >> 4;
    const int wr = w >> 1, wc = w & 1;
    const int m0 = blockIdx.x * 128;
    const int n0 = blockIdx.y * 128;

    const int sm = tid >> 2;
    const int sk = (tid & 3) << 3;

    f32x4 acc[4][4] = {};
    for (int k0 = 0; k0 < HID; k0 += 32) {
        bf16x8 a0 = *(const bf16x8*)&Ab[(size_t)(m0 + sm) * HID + k0 + sk];
        bf16x8 a1 = *(const bf16x8*)&Ab[(size_t)(m0 + 64 + sm) * HID + k0 + sk];
        bf16x8 b0 = *(const bf16x8*)&To[(size_t)(n0 + sm) * HID + k0 + sk];
        bf16x8 b1 = *(const bf16x8*)&To[(size_t)(n0 + 64 + sm) * HID + k0 + sk];
        __syncthreads();
        *(bf16x8*)&Al[sm][sk]      = a0;
        *(bf16x8*)&Al[64 + sm][sk] = a1;
        *(bf16x8*)&Bl[sm][sk]      = b0;
        *(bf16x8*)&Bl[64 + sm][sk] = b1;
        __syncthreads();
        bf16x8 af[4], bfr[4];
        #pragma unroll
        for (int i = 0; i < 4; ++i) {
            af[i]  = *(const bf16x8*)&Al[wr * 64 + i * 16 + l15][lg * 8];
            bfr[i] = *(const bf16x8*)&Bl[wc * 64 + i * 16 + l15][lg * 8];
        }
        #pragma unroll
        for (int mf = 0; mf < 4; ++mf)
            #pragma unroll
            for (int nf = 0; nf < 4; ++nf)
                acc[mf][nf] = __builtin_amdgcn_mfma_f32_16x16x32_bf16(af[mf], bfr[nf], acc[mf][nf], 0, 0, 0);
    }

    #pragma unroll
    for (int nf = 0; nf < 4; ++nf) {
        const int col = n0 + wc * 64 + nf * 16 + l15;
        const float bv_ = bo[col];
        #pragma unroll
        for (int mf = 0; mf < 4; ++mf)
            #pragma unroll
            for (int r = 0; r < 4; ++r) {
                const int m = m0 + wr * 64 + mf * 16 + lg * 4 + r;
                out[(size_t)m * HID + col] = acc[mf][nf][r] + bv_;
            }
    }
}

// ---------------------------------------------------------------------------
extern "C" void kernel_launch(void* const* d_in, const int* in_sizes, int n_in,
                              void* d_out, int out_size, void* d_ws, size_t ws_size,
                              hipStream_t stream) {
    int iX = 0, iWq = 1, ibq = 2, iWk = 3, ibk = 4, iWv = 5, ibv = 6, iWo = 7, ibo = 8;
    if (n_in == 9 && in_sizes[1] == 1048576) {   // alphabetical-order hedge
        iWk = 1; iWo = 2; iWq = 3; iWv = 4; ibk = 5; ibo = 6; ibq = 7; ibv = 8;
    }
    const float* X  = (const float*)d_in[iX];
    const float* Wq = (const float*)d_in[iWq];
    const float* bq = (const float*)d_in[ibq];
    const float* Wk = (const float*)d_in[iWk];
    const float* bk = (const float*)d_in[ibk];
    const float* Wv = (const float*)d_in[iWv];
    const float* bv = (const float*)d_in[ibv];
    const float* Wo = (const float*)d_in[iWo];
    const float* bo = (const float*)d_in[ibo];
    float* out = (float*)d_out;

    // bf16 workspace: 79.7 MB total
    u16* Xb  = (u16*)d_ws;                                  // [4096][2048]
    u16* Tq  = Xb  + (size_t)MM * HID;                      // [2048][2048] (W^T)
    u16* Tk  = Tq  + (size_t)HID * HID;                     // [512][2048]
    u16* Tv  = Tk  + (size_t)512 * HID;                     // [512][2048]
    u16* To  = Tv  + (size_t)512 * HID;                     // [2048][2048]
    u16* qws = To  + (size_t)HID * HID;                     // [2,32,2048,64]
    u16* kws = qws + (size_t)BB * NH  * SS_ * HD;           // [2,8,2048,64]
    u16* vws = kws + (size_t)BB * NKV * SS_ * HD;           // [2,8,2048,64]
    u16* ows = vws + (size_t)BB * NKV * SS_ * HD;           // [4096][2048]

    cvt_kernel<<<dim3((MM * HID / 4 + 255) / 256), 256, 0, stream>>>(X, Xb, MM * HID / 4);
    tw_kernel<<<dim3(32, 80), 256, 0, stream>>>(Wq, Wk, Wv, Wo, Tq, Tk, Tv, To);
    proj_kernel<<<dim3(32, 24), 256, 0, stream>>>(Xb, Tq, Tk, Tv, bq, bk, bv, qws, kws, vws);
    attn_kernel<<<dim3(16, 32, 2), 256, 0, stream>>>(qws, kws, vws, ows);
    oproj_kernel<<<dim3(32, 16), 256, 0, stream>>>(ows, To, bo, out);
}

// Round 8
// 380.674 us; speedup vs baseline: 6.4255x; 1.1079x over previous
//
#include <hip/hip_runtime.h>
#include <hip/hip_bf16.h>

#define HID 2048
#define NH 32
#define NKV 8
#define HD 64
#define BB 2
#define SS_ 2048
#define MM (BB * SS_)     // 4096 rows

#define QT 128            // q rows per attn block (4 waves x 32)
#define KT 64             // kv rows per tile
#define LDK 72            // padded stride (u16) for Ks  (144B rows, 16B-aligned)
#define LDV 68            // padded stride (u16) for Vt  (136B rows, 8B-aligned)
#define LDO 66            // padded stride (u16) for Ot

typedef unsigned short u16;
typedef __attribute__((ext_vector_type(8)))  short bf16x8;
typedef __attribute__((ext_vector_type(4)))  float f32x4;
typedef __attribute__((ext_vector_type(16))) float f32x16;

__device__ __forceinline__ u16 f2bf(float f) {
    union { float f; unsigned int i; } v; v.f = f;
    unsigned int lsb = (v.i >> 16) & 1u;
    v.i += 0x7fffu + lsb;               // round-to-nearest-even
    return (u16)(v.i >> 16);
}
// pack two f32 -> u32 of 2 bf16, LOW u16 = lo (RTN, no cvt_pk semantics risk)
__device__ __forceinline__ unsigned int pack_bf2(float lo, float hi) {
    return ((unsigned int)f2bf(hi) << 16) | (unsigned int)f2bf(lo);
}

// ---------------------------------------------------------------------------
// K0a: straight fp32 -> bf16 convert (X)
// ---------------------------------------------------------------------------
__global__ __launch_bounds__(256) void cvt_kernel(
    const float* __restrict__ in, u16* __restrict__ out, int n4)
{
    const int i = blockIdx.x * 256 + threadIdx.x;
    if (i < n4) {
        float4 f = ((const float4*)in)[i];
        ushort4 r;
        r.x = f2bf(f.x); r.y = f2bf(f.y); r.z = f2bf(f.z); r.w = f2bf(f.w);
        ((ushort4*)out)[i] = r;
    }
}

// ---------------------------------------------------------------------------
// K0b: transpose-convert weights: fp32 [K][N] -> bf16 [N][K].
// ---------------------------------------------------------------------------
__global__ __launch_bounds__(256) void tw_kernel(
    const float* __restrict__ Wq, const float* __restrict__ Wk,
    const float* __restrict__ Wv, const float* __restrict__ Wo,
    u16* __restrict__ Tq, u16* __restrict__ Tk,
    u16* __restrict__ Tv, u16* __restrict__ To)
{
    __shared__ float tile[64][65];
    const int by = blockIdx.y;
    const float* W; u16* T; int N, n0;
    if (by < 32)      { W = Wq; T = Tq; N = 2048; n0 = by * 64; }
    else if (by < 40) { W = Wk; T = Tk; N = 512;  n0 = (by - 32) * 64; }
    else if (by < 48) { W = Wv; T = Tv; N = 512;  n0 = (by - 40) * 64; }
    else              { W = Wo; T = To; N = 2048; n0 = (by - 48) * 64; }
    const int k0 = blockIdx.x * 64;
    const int r  = threadIdx.x >> 2;
    const int c0 = (threadIdx.x & 3) << 4;
    #pragma unroll
    for (int u = 0; u < 4; ++u) {
        float4 f = *(const float4*)&W[(size_t)(k0 + r) * N + n0 + c0 + u * 4];
        tile[r][c0 + u * 4 + 0] = f.x; tile[r][c0 + u * 4 + 1] = f.y;
        tile[r][c0 + u * 4 + 2] = f.z; tile[r][c0 + u * 4 + 3] = f.w;
    }
    __syncthreads();
    #pragma unroll
    for (int u = 0; u < 4; ++u) {
        ushort4 o;
        o.x = f2bf(tile[c0 + u * 4 + 0][r]);
        o.y = f2bf(tile[c0 + u * 4 + 1][r]);
        o.z = f2bf(tile[c0 + u * 4 + 2][r]);
        o.w = f2bf(tile[c0 + u * 4 + 3][r]);
        *(ushort4*)&T[(size_t)(n0 + r) * HID + k0 + c0 + u * 4] = o;
    }
}

// ---------------------------------------------------------------------------
// K1: QKV projection, bf16 MFMA (16x16x32), 128x128x32 tile — unchanged.
// ---------------------------------------------------------------------------
__global__ __launch_bounds__(256) void proj_kernel(
    const u16* __restrict__ Xb,
    const u16* __restrict__ Tq, const u16* __restrict__ Tk, const u16* __restrict__ Tv,
    const float* __restrict__ bq, const float* __restrict__ bk, const float* __restrict__ bv,
    u16* __restrict__ qo, u16* __restrict__ ko, u16* __restrict__ vo)
{
    __shared__ u16 Al[128][36];
    __shared__ u16 Bl[128][36];
    const int tid = threadIdx.x;
    const int w = tid >> 6, l15 = tid & 15, lg = (tid & 63) >> 4;
    const int wr = w >> 1, wc = w & 1;
    const int m0 = blockIdx.x * 128;
    const int n0 = blockIdx.y * 128;

    const u16* Bt; const float* bias; u16* dst; int nh, nb;
    if (n0 < 2048)      { Bt = Tq + (size_t)n0 * HID;          bias = bq + n0;          dst = qo; nh = NH;  nb = n0; }
    else if (n0 < 2560) { Bt = Tk + (size_t)(n0 - 2048) * HID; bias = bk + (n0 - 2048); dst = ko; nh = NKV; nb = n0 - 2048; }
    else                { Bt = Tv + (size_t)(n0 - 2560) * HID; bias = bv + (n0 - 2560); dst = vo; nh = NKV; nb = n0 - 2560; }

    const int sm = tid >> 2;
    const int sk = (tid & 3) << 3;

    f32x4 acc[4][4] = {};
    for (int k0 = 0; k0 < HID; k0 += 32) {
        bf16x8 a0 = *(const bf16x8*)&Xb[(size_t)(m0 + sm) * HID + k0 + sk];
        bf16x8 a1 = *(const bf16x8*)&Xb[(size_t)(m0 + 64 + sm) * HID + k0 + sk];
        bf16x8 b0 = *(const bf16x8*)&Bt[(size_t)sm * HID + k0 + sk];
        bf16x8 b1 = *(const bf16x8*)&Bt[(size_t)(64 + sm) * HID + k0 + sk];
        __syncthreads();
        *(bf16x8*)&Al[sm][sk]      = a0;
        *(bf16x8*)&Al[64 + sm][sk] = a1;
        *(bf16x8*)&Bl[sm][sk]      = b0;
        *(bf16x8*)&Bl[64 + sm][sk] = b1;
        __syncthreads();
        bf16x8 af[4], bfr[4];
        #pragma unroll
        for (int i = 0; i < 4; ++i) {
            af[i]  = *(const bf16x8*)&Al[wr * 64 + i * 16 + l15][lg * 8];
            bfr[i] = *(const bf16x8*)&Bl[wc * 64 + i * 16 + l15][lg * 8];
        }
        #pragma unroll
        for (int mf = 0; mf < 4; ++mf)
            #pragma unroll
            for (int nf = 0; nf < 4; ++nf)
                acc[mf][nf] = __builtin_amdgcn_mfma_f32_16x16x32_bf16(af[mf], bfr[nf], acc[mf][nf], 0, 0, 0);
    }

    #pragma unroll
    for (int nf = 0; nf < 4; ++nf) {
        const int cl = nb + wc * 64 + nf * 16 + l15;
        const int hh = cl >> 6, dd = cl & 63;
        const float bv_ = bias[wc * 64 + nf * 16 + l15];
        #pragma unroll
        for (int mf = 0; mf < 4; ++mf)
            #pragma unroll
            for (int r = 0; r < 4; ++r) {
                const int m = m0 + wr * 64 + mf * 16 + lg * 4 + r;
                const int bb_ = m >> 11, ss = m & (SS_ - 1);
                dst[(((size_t)bb_ * nh + hh) * SS_ + ss) * HD + dd] = f2bf(acc[mf][nf][r] + bv_);
            }
    }
}

// ---------------------------------------------------------------------------
// K2: flash attention, 32x32x16 bf16 MFMA, swapped QK^T, in-register P.
// Identical to round 7 EXCEPT: manual RTN pack replaces v_cvt_pk_bf16_f32
// (single-variable bisection of the cvt_pk-semantics assumption).
// ---------------------------------------------------------------------------
__global__ __launch_bounds__(256) void attn_kernel(
    const u16* __restrict__ q, const u16* __restrict__ k,
    const u16* __restrict__ v, u16* __restrict__ o)
{
    union SMem {
        struct { u16 Ks[KT][LDK]; u16 Vt[HD][LDV]; } s;
        u16 Ot[QT][LDO];
    };
    __shared__ SMem sm;

    const int tid = threadIdx.x;
    const int w   = tid >> 6;
    const int l   = tid & 63;
    const int l31 = l & 31;
    const int hi  = l >> 5;
    const int qt  = blockIdx.x;
    const int h   = blockIdx.y;
    const int b   = blockIdx.z;
    const int hk  = h >> 2;

    const u16* qb = q + (((size_t)b * NH  + h ) * SS_ + qt * QT) * HD;
    const u16* kp = k + (((size_t)b * NKV + hk) * SS_) * HD;
    const u16* vp = v + (((size_t)b * NKV + hk) * SS_) * HD;

    // Q B-frags: col = qrow = w*32+l31, k = d = kc*16 + hi*8 + j
    bf16x8 qf[4];
    #pragma unroll
    for (int kc = 0; kc < 4; ++kc)
        qf[kc] = *(const bf16x8*)&qb[(size_t)(w * 32 + l31) * HD + kc * 16 + hi * 8];

    f32x16 oaccT[2] = {};   // col=qrow=l31; row=d = db*32 + (r&3)+8*(r>>2)+4*hi
    float m_i = -3.0e38f, l_i = 0.f;

    const int krow = tid >> 2, kcol = (tid & 3) << 4;        // K staging
    const int vk0  = (tid & 15) << 2, vd0 = (tid >> 4) << 2; // V staging (4kv x 4d)

    for (int t = 0; t < SS_ / KT; ++t) {
        bf16x8 kr0 = *(const bf16x8*)&kp[(size_t)(t * KT + krow) * HD + kcol];
        bf16x8 kr1 = *(const bf16x8*)&kp[(size_t)(t * KT + krow) * HD + kcol + 8];
        uint2 vv[4];
        #pragma unroll
        for (int i = 0; i < 4; ++i)
            vv[i] = *(const uint2*)&vp[(size_t)(t * KT + vk0 + i) * HD + vd0];
        __syncthreads();   // previous iteration done reading Ks/Vt
        *(bf16x8*)&sm.s.Ks[krow][kcol]     = kr0;
        *(bf16x8*)&sm.s.Ks[krow][kcol + 8] = kr1;
        #pragma unroll
        for (int j = 0; j < 4; ++j) {      // 4x4 register transpose -> b64 writes
            ushort4 tv;
            tv.x = ((const u16*)&vv[0])[j];
            tv.y = ((const u16*)&vv[1])[j];
            tv.z = ((const u16*)&vv[2])[j];
            tv.w = ((const u16*)&vv[3])[j];
            *(ushort4*)&sm.s.Vt[vd0 + j][vk0] = tv;
        }
        __syncthreads();

        // ---- S^T = K · Q^T
        f32x16 st[2] = {};
        #pragma unroll
        for (int kb = 0; kb < 2; ++kb)
            #pragma unroll
            for (int kc = 0; kc < 4; ++kc) {
                bf16x8 kf = *(const bf16x8*)&sm.s.Ks[kb * 32 + l31][kc * 16 + hi * 8];
                st[kb] = __builtin_amdgcn_mfma_f32_32x32x16_bf16(kf, qf[kc], st[kb], 0, 0, 0);
            }

        // ---- online softmax over kv (scale 0.125 folded into exp args)
        float x0 = st[0][0], x1 = st[0][1], x2 = st[0][2], x3 = st[0][3];
        #pragma unroll
        for (int r = 4; r < 16; r += 4) {
            x0 = fmaxf(x0, st[0][r + 0]); x1 = fmaxf(x1, st[0][r + 1]);
            x2 = fmaxf(x2, st[0][r + 2]); x3 = fmaxf(x3, st[0][r + 3]);
        }
        #pragma unroll
        for (int r = 0; r < 16; r += 4) {
            x0 = fmaxf(x0, st[1][r + 0]); x1 = fmaxf(x1, st[1][r + 1]);
            x2 = fmaxf(x2, st[1][r + 2]); x3 = fmaxf(x3, st[1][r + 3]);
        }
        float pmax = fmaxf(fmaxf(x0, x1), fmaxf(x2, x3));
        pmax = fmaxf(pmax, __shfl_xor(pmax, 32));
        const float mn = fmaxf(m_i, pmax);
        const float al = __expf((m_i - mn) * 0.125f);
        m_i = mn;
        float s0 = 0.f, s1 = 0.f, s2 = 0.f, s3 = 0.f;
        #pragma unroll
        for (int kb = 0; kb < 2; ++kb)
            #pragma unroll
            for (int r = 0; r < 16; r += 4) {
                const float p0 = __expf((st[kb][r + 0] - mn) * 0.125f);
                const float p1 = __expf((st[kb][r + 1] - mn) * 0.125f);
                const float p2 = __expf((st[kb][r + 2] - mn) * 0.125f);
                const float p3 = __expf((st[kb][r + 3] - mn) * 0.125f);
                st[kb][r + 0] = p0; st[kb][r + 1] = p1;
                st[kb][r + 2] = p2; st[kb][r + 3] = p3;
                s0 += p0; s1 += p1; s2 += p2; s3 += p3;
            }
        float rs = (s0 + s1) + (s2 + s3);
        rs += __shfl_xor(rs, 32);
        l_i = l_i * al + rs;
        #pragma unroll
        for (int db = 0; db < 2; ++db)
            #pragma unroll
            for (int r = 0; r < 16; ++r) oaccT[db][r] *= al;

        // ---- P -> packed bf16 pairs (manual RTN pack), own + partner halves
        unsigned int pk[2][8], pq[2][8];
        #pragma unroll
        for (int kb = 0; kb < 2; ++kb)
            #pragma unroll
            for (int s = 0; s < 8; ++s) {
                unsigned int r_ = pack_bf2(st[kb][2 * s], st[kb][2 * s + 1]);
                pk[kb][s] = r_;
                pq[kb][s] = (unsigned int)__shfl_xor((int)r_, 32);
            }

        // ---- O^T += V^T · P^T   (A = V^T frag, B = P frag)
        #pragma unroll
        for (int kc = 0; kc < 4; ++kc) {
            const int kb = kc >> 1, c4 = (kc & 1) * 4;
            uint4 pbu;
            pbu.x = hi ? pq[kb][c4 + 2] : pk[kb][c4 + 0];
            pbu.y = hi ? pq[kb][c4 + 3] : pk[kb][c4 + 1];
            pbu.z = hi ? pk[kb][c4 + 2] : pq[kb][c4 + 0];
            pbu.w = hi ? pk[kb][c4 + 3] : pq[kb][c4 + 1];
            bf16x8 pb = *(bf16x8*)&pbu;
            #pragma unroll
            for (int db = 0; db < 2; ++db) {
                bf16x8 vf = *(const bf16x8*)&sm.s.Vt[db * 32 + l31][kc * 16 + hi * 8];
                oaccT[db] = __builtin_amdgcn_mfma_f32_32x32x16_bf16(vf, pb, oaccT[db], 0, 0, 0);
            }
        }
    }

    // ---- epilogue: normalize, transpose via LDS, coalesced bf16 stores
    const float inv = 1.0f / l_i;
    __syncthreads();   // done with Ks/Vt (union reuse)
    #pragma unroll
    for (int db = 0; db < 2; ++db)
        #pragma unroll
        for (int p = 0; p < 8; ++p) {
            const int d0 = db * 32 + 2 * (p & 1) + 4 * hi + 8 * (p >> 1);
            unsigned int r_ = pack_bf2(oaccT[db][2 * p] * inv, oaccT[db][2 * p + 1] * inv);
            *(unsigned int*)&sm.Ot[w * 32 + l31][d0] = r_;
        }
    __syncthreads();
    {
        const int row = tid >> 1, half = tid & 1;
        u16* go = o + ((size_t)b * SS_ + qt * QT + row) * HID + h * HD + half * 32;
        #pragma unroll
        for (int u = 0; u < 2; ++u) {
            uint4 t0 = *(uint4*)&sm.Ot[row][half * 32 + u * 16];
            *(uint4*)&go[u * 16] = t0;
            uint4 t1 = *(uint4*)&sm.Ot[row][half * 32 + u * 16 + 8];
            *(uint4*)&go[u * 16 + 8] = t1;
        }
    }
}

// ---------------------------------------------------------------------------
// K3: output projection, bf16 MFMA — unchanged.
// ---------------------------------------------------------------------------
__global__ __launch_bounds__(256) void oproj_kernel(
    const u16* __restrict__ Ab, const u16* __restrict__ To,
    const float* __restrict__ bo, float* __restrict__ out)
{
    __shared__ u16 Al[128][36];
    __shared__ u16 Bl[128][36];
    const int tid = threadIdx.x;
    const int w = tid >> 6, l15 = tid & 15, lg = (tid & 63) >> 4;
    const int wr = w >> 1, wc = w & 1;
    const int m0 = blockIdx.x * 128;
    const int n0 = blockIdx.y * 128;

    const int sm = tid >> 2;
    const int sk = (tid & 3) << 3;

    f32x4 acc[4][4] = {};
    for (int k0 = 0; k0 < HID; k0 += 32) {
        bf16x8 a0 = *(const bf16x8*)&Ab[(size_t)(m0 + sm) * HID + k0 + sk];
        bf16x8 a1 = *(const bf16x8*)&Ab[(size_t)(m0 + 64 + sm) * HID + k0 + sk];
        bf16x8 b0 = *(const bf16x8*)&To[(size_t)(n0 + sm) * HID + k0 + sk];
        bf16x8 b1 = *(const bf16x8*)&To[(size_t)(n0 + 64 + sm) * HID + k0 + sk];
        __syncthreads();
        *(bf16x8*)&Al[sm][sk]      = a0;
        *(bf16x8*)&Al[64 + sm][sk] = a1;
        *(bf16x8*)&Bl[sm][sk]      = b0;
        *(bf16x8*)&Bl[64 + sm][sk] = b1;
        __syncthreads();
        bf16x8 af[4], bfr[4];
        #pragma unroll
        for (int i = 0; i < 4; ++i) {
            af[i]  = *(const bf16x8*)&Al[wr * 64 + i * 16 + l15][lg * 8];
            bfr[i] = *(const bf16x8*)&Bl[wc * 64 + i * 16 + l15][lg * 8];
        }
        #pragma unroll
        for (int mf = 0; mf < 4; ++mf)
            #pragma unroll
            for (int nf = 0; nf < 4; ++nf)
                acc[mf][nf] = __builtin_amdgcn_mfma_f32_16x16x32_bf16(af[mf], bfr[nf], acc[mf][nf], 0, 0, 0);
    }

    #pragma unroll
    for (int nf = 0; nf < 4; ++nf) {
        const int col = n0 + wc * 64 + nf * 16 + l15;
        const float bv_ = bo[col];
        #pragma unroll
        for (int mf = 0; mf < 4; ++mf)
            #pragma unroll
            for (int r = 0; r < 4; ++r) {
                const int m = m0 + wr * 64 + mf * 16 + lg * 4 + r;
                out[(size_t)m * HID + col] = acc[mf][nf][r] + bv_;
            }
    }
}

// ---------------------------------------------------------------------------
extern "C" void kernel_launch(void* const* d_in, const int* in_sizes, int n_in,
                              void* d_out, int out_size, void* d_ws, size_t ws_size,
                              hipStream_t stream) {
    int iX = 0, iWq = 1, ibq = 2, iWk = 3, ibk = 4, iWv = 5, ibv = 6, iWo = 7, ibo = 8;
    if (n_in == 9 && in_sizes[1] == 1048576) {   // alphabetical-order hedge
        iWk = 1; iWo = 2; iWq = 3; iWv = 4; ibk = 5; ibo = 6; ibq = 7; ibv = 8;
    }
    const float* X  = (const float*)d_in[iX];
    const float* Wq = (const float*)d_in[iWq];
    const float* bq = (const float*)d_in[ibq];
    const float* Wk = (const float*)d_in[iWk];
    const float* bk = (const float*)d_in[ibk];
    const float* Wv = (const float*)d_in[iWv];
    const float* bv = (const float*)d_in[ibv];
    const float* Wo = (const float*)d_in[iWo];
    const float* bo = (const float*)d_in[ibo];
    float* out = (float*)d_out;

    u16* Xb  = (u16*)d_ws;                                  // [4096][2048]
    u16* Tq  = Xb  + (size_t)MM * HID;                      // [2048][2048]
    u16* Tk  = Tq  + (size_t)HID * HID;                     // [512][2048]
    u16* Tv  = Tk  + (size_t)512 * HID;                     // [512][2048]
    u16* To  = Tv  + (size_t)512 * HID;                     // [2048][2048]
    u16* qws = To  + (size_t)HID * HID;                     // [2,32,2048,64]
    u16* kws = qws + (size_t)BB * NH  * SS_ * HD;           // [2,8,2048,64]
    u16* vws = kws + (size_t)BB * NKV * SS_ * HD;           // [2,8,2048,64]
    u16* ows = vws + (size_t)BB * NKV * SS_ * HD;           // [4096][2048]

    cvt_kernel<<<dim3((MM * HID / 4 + 255) / 256), 256, 0, stream>>>(X, Xb, MM * HID / 4);
    tw_kernel<<<dim3(32, 80), 256, 0, stream>>>(Wq, Wk, Wv, Wo, Tq, Tk, Tv, To);
    proj_kernel<<<dim3(32, 24), 256, 0, stream>>>(Xb, Tq, Tk, Tv, bq, bk, bv, qws, kws, vws);
    attn_kernel<<<dim3(16, 32, 2), 256, 0, stream>>>(qws, kws, vws, ows);
    oproj_kernel<<<dim3(32, 16), 256, 0, stream>>>(ows, To, bo, out);
}